// Round 8
// baseline (36.802 us; speedup 1.0000x reference)
//
#include <hip/hip_runtime.h>

// out[b,h] = (X X^T) X == X (X^T X) per head; X = x[b,h] : [2048 x 64] fp32.
// Two dispatches, NO cross-block sync, NO coherent(sc0sc1) traffic:
//  K1: DMA-stage 2x64 rows (overlapped via vmcnt(4)+raw barrier) -> partial
//      Gram -> plain cached row-major stores (kernel boundary publishes).
//  K2: issue x DMA, then EVERY block redundantly reduces the full 64x64 G
//      from its head's 16 partials (plain cached loads, L2/L3-hot, overlaps
//      the DMA) -> LDS -> out = X G. Deterministic fixed-order sums.

#define TDIM 2048
#define DDIM 64
#define NHEADS 32
#define NPAIR 16
#define NBLOCKS (NHEADS * NPAIR)          // 512

typedef float f4 __attribute__((ext_vector_type(4)));

// Async global->LDS DMA, 16 B/lane. LDS dest wave-uniform; lane l -> dest+l*16.
__device__ __forceinline__ void async_copy16(const float* g, float* l) {
    __builtin_amdgcn_global_load_lds(
        (const __attribute__((address_space(1))) void*)g,
        (__attribute__((address_space(3))) void*)l, 16, 0, 0);
}

__device__ __forceinline__ void gram_tile(const float* buf, int i0, int j0,
                                          float acc[4][4]) {
#pragma unroll 8
    for (int t = 0; t < 64; ++t) {
        const float4 av = *reinterpret_cast<const float4*>(&buf[t * 64 + i0]);
        const float4 bv = *reinterpret_cast<const float4*>(&buf[t * 64 + j0]);
        const float aa[4] = {av.x, av.y, av.z, av.w};
        const float bb[4] = {bv.x, bv.y, bv.z, bv.w};
#pragma unroll
        for (int a = 0; a < 4; ++a)
#pragma unroll
            for (int q = 0; q < 4; ++q) acc[a][q] += aa[a] * bb[q];
    }
}

__device__ __forceinline__ void xg_tile(const float* xsb, const float* Gs,
                                        int r0, int d0, float* oh) {
    float acc[4][4];
#pragma unroll
    for (int a = 0; a < 4; ++a)
#pragma unroll
        for (int q = 0; q < 4; ++q) acc[a][q] = 0.f;
#pragma unroll 4
    for (int i = 0; i < 64; i += 4) {
        float4 g[4], xv[4];
#pragma unroll
        for (int ii = 0; ii < 4; ++ii)
            g[ii] = *reinterpret_cast<const float4*>(&Gs[(i + ii) * 64 + d0]);
#pragma unroll
        for (int k = 0; k < 4; ++k)
            xv[k] = *reinterpret_cast<const float4*>(&xsb[(r0 + k) * 64 + i]);
#pragma unroll
        for (int k = 0; k < 4; ++k) {
            const float xk[4] = {xv[k].x, xv[k].y, xv[k].z, xv[k].w};
#pragma unroll
            for (int ii = 0; ii < 4; ++ii) {
                acc[k][0] += xk[ii] * g[ii].x;
                acc[k][1] += xk[ii] * g[ii].y;
                acc[k][2] += xk[ii] * g[ii].z;
                acc[k][3] += xk[ii] * g[ii].w;
            }
        }
    }
#pragma unroll
    for (int k = 0; k < 4; ++k)
        *reinterpret_cast<float4*>(oh + (size_t)(r0 + k) * DDIM + d0) =
            make_float4(acc[k][0], acc[k][1], acc[k][2], acc[k][3]);
}

// ---------------- K1: partial Gram, all-cached, overlapped stage ------------
__global__ __launch_bounds__(256) void k1_gram(const float* __restrict__ x,
                                               float* __restrict__ part) {
    __shared__ float bufA[4096];
    __shared__ float bufB[4096];

    const int b    = blockIdx.x;
    const int tid  = threadIdx.x;
    const int lane = tid & 63;
    const int wv   = tid >> 6;
    const int head = b >> 4;
    const int pair = b & 15;

    const float* xh = x + ((size_t)head * TDIM + pair * 128) * DDIM;
    const float* g0 = xh + wv * 1024 + lane * 4;
    const float* g1 = g0 + 4096;                 // +64 rows

#pragma unroll
    for (int it = 0; it < 4; ++it)
        async_copy16(g0 + it * 256, bufA + wv * 1024 + it * 256);
#pragma unroll
    for (int it = 0; it < 4; ++it)
        async_copy16(g1 + it * 256, bufB + wv * 1024 + it * 256);

    // bufA ready: each wave's 4 A-loads are its oldest VMEM ops.
    asm volatile("s_waitcnt vmcnt(4)" ::: "memory");
    __builtin_amdgcn_sched_barrier(0);
    __builtin_amdgcn_s_barrier();

    const int i0 = (tid >> 4) << 2;
    const int j0 = (tid & 15) << 2;
    float acc[4][4];
#pragma unroll
    for (int a = 0; a < 4; ++a)
#pragma unroll
        for (int q = 0; q < 4; ++q) acc[a][q] = 0.f;

    gram_tile(bufA, i0, j0, acc);   // bufB DMA drains underneath

    asm volatile("s_waitcnt vmcnt(0)" ::: "memory");
    __builtin_amdgcn_sched_barrier(0);
    __builtin_amdgcn_s_barrier();

    gram_tile(bufB, i0, j0, acc);

    // Row-major partial store: per instr, waves write 4x256B chunks (1 KB).
    float* p = part + (size_t)b * 4096;
#pragma unroll
    for (int a = 0; a < 4; ++a)
        *reinterpret_cast<f4*>(p + (i0 + a) * 64 + j0) =
            f4{acc[a][0], acc[a][1], acc[a][2], acc[a][3]};
}

// ---------------- K2: redundant G reduce + XG, no sync ----------------------
__global__ __launch_bounds__(256) void k2_xg(const float* __restrict__ x,
                                             float* __restrict__ out,
                                             const float* __restrict__ part) {
    __shared__ float bufA[4096];
    __shared__ float bufB[4096];
    __shared__ float Gs[4096];

    const int b    = blockIdx.x;
    const int tid  = threadIdx.x;
    const int lane = tid & 63;
    const int wv   = tid >> 6;
    const int head = b >> 4;
    const int pair = b & 15;

    const float* xh = x + ((size_t)head * TDIM + pair * 128) * DDIM;

    // Issue x DMA first; it drains under the G reduce.
    {
        const float* g0 = xh + wv * 1024 + lane * 4;
        const float* g1 = g0 + 4096;
#pragma unroll
        for (int it = 0; it < 4; ++it) {
            async_copy16(g0 + it * 256, bufA + wv * 1024 + it * 256);
            async_copy16(g1 + it * 256, bufB + wv * 1024 + it * 256);
        }
    }

    // Redundant full-G reduce: this block sums all 16 partials of its head.
    // Plain cached loads (published by kernel boundary; L2/L3-hot).
    // Thread owns G float4-chunks {tid, tid+1024, tid+2048, tid+3072}:
    // every load instruction is 1 KB wave-contiguous.
    {
        const float* ph = part + (size_t)head * NPAIR * 4096 + tid * 4;
        f4 a0 = {0.f, 0.f, 0.f, 0.f}, a1 = a0, a2 = a0, a3 = a0;
#pragma unroll
        for (int c = 0; c < NPAIR; ++c) {
            const float* pc = ph + (size_t)c * 4096;
            a0 += *reinterpret_cast<const f4*>(pc);
            a1 += *reinterpret_cast<const f4*>(pc + 1024);
            a2 += *reinterpret_cast<const f4*>(pc + 2048);
            a3 += *reinterpret_cast<const f4*>(pc + 3072);
        }
        *reinterpret_cast<f4*>(&Gs[tid * 4])        = a0;
        *reinterpret_cast<f4*>(&Gs[tid * 4 + 1024]) = a1;
        *reinterpret_cast<f4*>(&Gs[tid * 4 + 2048]) = a2;
        *reinterpret_cast<f4*>(&Gs[tid * 4 + 3072]) = a3;
    }
    __syncthreads();   // drains DMA (vmcnt0) + publishes Gs (lgkmcnt0)

    const int r0 = (tid >> 4) << 2;
    const int d0 = (tid & 15) << 2;
    float* oh = out + ((size_t)head * TDIM + pair * 128) * DDIM;
    xg_tile(bufA, Gs, r0, d0, oh);
    xg_tile(bufB, Gs, r0, d0, oh + 64 * DDIM);
}

extern "C" void kernel_launch(void* const* d_in, const int* in_sizes, int n_in,
                              void* d_out, int out_size, void* d_ws, size_t ws_size,
                              hipStream_t stream) {
    const float* x = (const float*)d_in[0];
    float* out = (float*)d_out;
    float* part = (float*)d_ws;   // 512 * 4096 floats = 8.4 MB

    k1_gram<<<NBLOCKS, 256, 0, stream>>>(x, part);
    k2_xg<<<NBLOCKS, 256, 0, stream>>>(x, out, part);
}

// Round 9
// 29.221 us; speedup vs baseline: 1.2595x; 1.2595x over previous
//
#include <hip/hip_runtime.h>

// out[b,h] = (X X^T) X == X (X^T X) per head; X = x[b,h] : [2048 x 64] fp32.
// MFMA bf16 version (fp32 accumulate):
//  K1 (512 blocks, 128 rows): DMA f32 -> LDS; convert to bf16 TRANSPOSED
//     XOR-swizzled tile XT[64][128]; partial Gram via mfma_f32_16x16x32_bf16.
//     A/B fragments are both loaded k-contiguous => any HW k-permutation
//     cancels (same pi on both operands). Plain cached partial stores.
//  K2 (256 blocks, 256 rows): redundant fp32 reduce of 16 partials -> G;
//     G -> bf16 LDS (G symmetric => B-operand "transpose" = row read);
//     X -> bf16 row-major swizzled; out = X*G via MFMA. C/D layout per m89:
//     col = lane&15, row = (lane>>4)*4 + reg.

#define TDIM 2048
#define DDIM 64
#define NHEADS 32

typedef float f4 __attribute__((ext_vector_type(4)));
typedef float f32x4 __attribute__((ext_vector_type(4)));
typedef short bf16x8 __attribute__((ext_vector_type(8)));
typedef short s4 __attribute__((ext_vector_type(4)));

// Async global->LDS DMA, 16 B/lane. LDS dest wave-uniform; lane l -> dest+l*16.
__device__ __forceinline__ void async_copy16(const float* g, float* l) {
    __builtin_amdgcn_global_load_lds(
        (const __attribute__((address_space(1))) void*)g,
        (__attribute__((address_space(3))) void*)l, 16, 0, 0);
}

// f32 -> bf16 bits, round-to-nearest-even.
__device__ __forceinline__ short f2bf(float f) {
    unsigned u = __builtin_bit_cast(unsigned, f);
    unsigned r = (u + 0x7fffu + ((u >> 16) & 1u)) >> 16;
    return (short)r;
}

// Swizzled fragment pointer: row-major bf16 tile, rowlen shorts per row,
// element kelem.. kelem+7 read as 16 B. Byte offset XORed with (row&7)<<4
// (bits 4-6) -> bank-spread, 16 B alignment preserved.
__device__ __forceinline__ const bf16x8* fragp(const short* base, int row,
                                               int rowlen, int kelem) {
    const char* p = (const char*)(base + row * rowlen);
    return (const bf16x8*)(p + ((kelem * 2) ^ ((row & 7) << 4)));
}

// ---------------- K1: partial Gram via MFMA ----------------
__global__ __launch_bounds__(256) void k1_gram(const float* __restrict__ x,
                                               float* __restrict__ part) {
    __shared__ __align__(16) float Sf[8192];      // 32 KB f32 stage
    __shared__ __align__(16) short XT[64 * 128];  // 16 KB bf16, transposed+swz

    const int b    = blockIdx.x;        // 0..511
    const int tid  = threadIdx.x;
    const int lane = tid & 63;
    const int w    = tid >> 6;
    const int head = b >> 4, ch = b & 15;

    const float* xh = x + ((size_t)head * TDIM + ch * 128) * DDIM;

    {   // DMA 128x64 f32
        const float* gs = xh + w * 2048 + lane * 4;
        float* ld = Sf + w * 2048;
#pragma unroll
        for (int it = 0; it < 8; ++it)
            async_copy16(gs + it * 256, ld + it * 256);
    }
    __syncthreads();   // vmcnt drained by compiler before s_barrier

    // convert + transpose: XT[col c][t] = bf16(X[t][c]), swizzled
#pragma unroll 8
    for (int e = 0; e < 32; ++e) {
        const int idx = e * 256 + tid;
        const int r = idx >> 6, c = idx & 63;
        XT[c * 128 + ((((r << 1)) ^ ((c & 7) << 4)) >> 1)] = f2bf(Sf[idx]);
    }
    __syncthreads();

    const int li = lane & 15, g = lane >> 4;
    const int iq0 = (w >> 1) * 2, jq0 = (w & 1) * 2;  // wave's 2x2 tile quad

    f32x4 acc[2][2];
#pragma unroll
    for (int a = 0; a < 2; ++a)
#pragma unroll
        for (int q = 0; q < 2; ++q) acc[a][q] = (f32x4){0.f, 0.f, 0.f, 0.f};

#pragma unroll
    for (int k0 = 0; k0 < 128; k0 += 32) {
        bf16x8 af[2], bv[2];
        af[0] = *fragp(XT, (iq0 + 0) * 16 + li, 128, k0 + 8 * g);
        af[1] = *fragp(XT, (iq0 + 1) * 16 + li, 128, k0 + 8 * g);
        bv[0] = *fragp(XT, (jq0 + 0) * 16 + li, 128, k0 + 8 * g);
        bv[1] = *fragp(XT, (jq0 + 1) * 16 + li, 128, k0 + 8 * g);
#pragma unroll
        for (int a = 0; a < 2; ++a)
#pragma unroll
            for (int q = 0; q < 2; ++q)
                acc[a][q] = __builtin_amdgcn_mfma_f32_16x16x32_bf16(
                    af[a], bv[q], acc[a][q], 0, 0, 0);
    }

    // C layout (m89): row = g*4 + reg, col = li (within 16x16 tile)
    float* pp = part + (size_t)b * 4096;
#pragma unroll
    for (int a = 0; a < 2; ++a)
#pragma unroll
        for (int d = 0; d < 2; ++d)
#pragma unroll
            for (int q = 0; q < 4; ++q)
                pp[((iq0 + a) * 16 + g * 4 + q) * 64 + (jq0 + d) * 16 + li] =
                    acc[a][d][q];
}

// ---------------- K2: redundant reduce + XG via MFMA ----------------
__global__ __launch_bounds__(256) void k2_xg(const float* __restrict__ x,
                                             float* __restrict__ out,
                                             const float* __restrict__ part) {
    __shared__ __align__(16) float Sf[8192];      // 32 KB f32 stage
    __shared__ __align__(16) short Xb[128 * 64];  // 16 KB bf16 row-major swz
    __shared__ __align__(16) short Gb[64 * 64];   // 8 KB bf16 G, swz

    const int b    = blockIdx.x;        // 0..255
    const int tid  = threadIdx.x;
    const int lane = tid & 63;
    const int w    = tid >> 6;
    const int head = b >> 3, ch = b & 7;

    const float* xh = x + ((size_t)head * TDIM + ch * 256) * DDIM;

    {   // issue DMA half 0 (overlaps the reduce)
        const float* gs = xh + w * 2048 + lane * 4;
        float* ld = Sf + w * 2048;
#pragma unroll
        for (int it = 0; it < 8; ++it)
            async_copy16(gs + it * 256, ld + it * 256);
    }

    // redundant fixed-order G reduce (plain cached; published by K1 boundary)
    {
        const float* ph = part + (size_t)head * 16 * 4096 + tid * 4;
        f4 av[4];
#pragma unroll
        for (int k = 0; k < 4; ++k) av[k] = (f4){0.f, 0.f, 0.f, 0.f};
#pragma unroll
        for (int c = 0; c < 16; ++c) {
            const float* pc = ph + (size_t)c * 4096;
#pragma unroll
            for (int k = 0; k < 4; ++k)
                av[k] += *reinterpret_cast<const f4*>(pc + k * 1024);
        }
#pragma unroll
        for (int k = 0; k < 4; ++k)
#pragma unroll
            for (int q = 0; q < 4; ++q) {
                const int idx = k * 1024 + tid * 4 + q;  // linear i*64+d
                const int i = idx >> 6, d = idx & 63;
                Gb[d * 64 + ((((i << 1)) ^ ((d & 7) << 4)) >> 1)] =
                    f2bf(av[k][q]);
            }
    }
    __syncthreads();   // Sf half0 + Gb ready

    const int li = lane & 15, g = lane >> 4;

    for (int half = 0; half < 2; ++half) {
        // convert Sf -> Xb (row-major, swizzled), 4-wide
#pragma unroll
        for (int e = 0; e < 8; ++e) {
            const int i4 = e * 256 + tid;          // f4 index in 2048
            const int r = i4 >> 4, c4 = (i4 & 15) << 2;
            const f4 v = *reinterpret_cast<const f4*>(Sf + (i4 << 2));
            s4 pk;
            pk[0] = f2bf(v[0]); pk[1] = f2bf(v[1]);
            pk[2] = f2bf(v[2]); pk[3] = f2bf(v[3]);
            *(s4*)((char*)Xb + r * 128 + (((c4 << 1)) ^ ((r & 7) << 4))) = pk;
        }
        __syncthreads();   // Xb ready

        if (half == 0) {   // issue DMA half 1 into Sf (now free)
            const float* gs = xh + 8192 + w * 2048 + lane * 4;
            float* ld = Sf + w * 2048;
#pragma unroll
            for (int it = 0; it < 8; ++it)
                async_copy16(gs + it * 256, ld + it * 256);
        }

        // MFMA: wave w owns row-tiles {2w, 2w+1} x col-tiles 0..3
        f32x4 acc[2][4];
#pragma unroll
        for (int r = 0; r < 2; ++r)
#pragma unroll
            for (int d = 0; d < 4; ++d) acc[r][d] = (f32x4){0.f, 0.f, 0.f, 0.f};

#pragma unroll
        for (int k0 = 0; k0 < 64; k0 += 32) {
            bf16x8 af[2], bv[4];
            af[0] = *fragp(Xb, (w * 2 + 0) * 16 + li, 64, k0 + 8 * g);
            af[1] = *fragp(Xb, (w * 2 + 1) * 16 + li, 64, k0 + 8 * g);
#pragma unroll
            for (int d = 0; d < 4; ++d)
                bv[d] = *fragp(Gb, d * 16 + li, 64, k0 + 8 * g);
#pragma unroll
            for (int r = 0; r < 2; ++r)
#pragma unroll
                for (int d = 0; d < 4; ++d)
                    acc[r][d] = __builtin_amdgcn_mfma_f32_16x16x32_bf16(
                        af[r], bv[d], acc[r][d], 0, 0, 0);
        }

        float* oh = out + ((size_t)head * TDIM + ch * 256 + half * 128) * DDIM;
#pragma unroll
        for (int r = 0; r < 2; ++r)
#pragma unroll
            for (int d = 0; d < 4; ++d)
#pragma unroll
                for (int q = 0; q < 4; ++q)
                    oh[((w * 2 + r) * 16 + g * 4 + q) * 64 + d * 16 + li] =
                        acc[r][d][q];

        __syncthreads();   // drains half-1 DMA; protects Xb overwrite
    }
}

extern "C" void kernel_launch(void* const* d_in, const int* in_sizes, int n_in,
                              void* d_out, int out_size, void* d_ws, size_t ws_size,
                              hipStream_t stream) {
    const float* x = (const float*)d_in[0];
    float* out = (float*)d_out;
    float* part = (float*)d_ws;   // 512 * 4096 floats = 8.4 MB

    k1_gram<<<512, 256, 0, stream>>>(x, part);
    k2_xg<<<256, 256, 0, stream>>>(x, out, part);
}